// Round 1
// baseline (3876.238 us; speedup 1.0000x reference)
//
#include <hip/hip_runtime.h>
#include <math.h>

#define NN 10000
#define NE 40000
#define NGRAPH 64
#define HID 64
#define EDIM 16
#define NLAYERS 3

// fused message kernel geometry
#define OSUB 8
#define NSLICE 8
#define GNODES 8
#define NGROUPS (NN / GNODES)   // 1250
#define NBLK 32
#define WCOLS 512               // 64 k * 8 o
#define BSTRIDE 520             // padded Bn stride (bank spread)
#define MSG_THREADS 512
#define MSG_LDS_FLOATS (64*WCOLS + GNODES*BSTRIDE + 64*GNODES)

__device__ __forceinline__ float silu_f(float x) { return x / (1.f + expf(-x)); }

// ---------------- small row GEMM: out[M][64] = act(A[M][K] @ W[K][64] + bias) ----
template<int K, bool DO_SILU, bool HAS_BIAS>
__global__ __launch_bounds__(256)
void k_rowmm(const float* __restrict__ A, const float* __restrict__ W,
             const float* __restrict__ bias, float* __restrict__ out, int M) {
    __shared__ float Ws[K * 64];
    __shared__ float As[4 * K];
    const int tid = threadIdx.x;
    for (int idx = tid; idx < K * 64; idx += 256) Ws[idx] = W[idx];
    const int r0 = blockIdx.x * 4;
    for (int idx = tid; idx < 4 * K; idx += 256) {
        int r = r0 + idx / K;
        As[idx] = (r < M) ? A[(size_t)r * K + (idx % K)] : 0.f;
    }
    __syncthreads();
    const int rr = tid >> 6, c = tid & 63;
    const int r = r0 + rr;
    if (r >= M) return;
    float s = HAS_BIAS ? bias[c] : 0.f;
#pragma unroll
    for (int k = 0; k < K; k++) s += As[rr * K + k] * Ws[k * 64 + c];
    if (DO_SILU) s = silu_f(s);
    out[(size_t)r * 64 + c] = s;
}

// ---------------- degree histogram + src counts ----------------
__global__ void k_hist(const int* __restrict__ ei, float* __restrict__ degf,
                       int* __restrict__ cnt) {
    int e = blockIdx.x * 256 + threadIdx.x;
    if (e >= NE) return;
    int s = ei[e], d = ei[NE + e];
    atomicAdd(&cnt[s], 1);
    atomicAdd(&degf[d], 1.f);
}

__global__ void k_invdeg(const float* __restrict__ degf, float* __restrict__ invd) {
    int n = blockIdx.x * 256 + threadIdx.x;
    if (n < NN) {
        float d = degf[n];
        invd[n] = (d > 0.f) ? 1.f / d : 0.f;
    }
}

// ---------------- single-block exclusive scan over NN counts ----------------
__global__ __launch_bounds__(1024)
void k_scan(const int* __restrict__ cnt, int* __restrict__ off, int* __restrict__ cur) {
    __shared__ int part[1024];
    const int t = threadIdx.x;
    const int CH = (NN + 1023) / 1024;  // 10
    const int base0 = t * CH;
    int s = 0;
    for (int i = 0; i < CH; i++) {
        int idx = base0 + i;
        if (idx < NN) s += cnt[idx];
    }
    part[t] = s;
    __syncthreads();
    for (int d = 1; d < 1024; d <<= 1) {
        int v = (t >= d) ? part[t - d] : 0;
        __syncthreads();
        part[t] += v;
        __syncthreads();
    }
    int run = (t == 0) ? 0 : part[t - 1];
    for (int i = 0; i < CH; i++) {
        int idx = base0 + i;
        if (idx < NN) {
            off[idx] = run;
            run += cnt[idx];
            cur[idx] = 0;
        }
    }
    if (t == 1023) off[NN] = run;
}

__global__ void k_fill(const int* __restrict__ ei, const int* __restrict__ off,
                       int* __restrict__ cur, int* __restrict__ eid) {
    int e = blockIdx.x * 256 + threadIdx.x;
    if (e >= NE) return;
    int s = ei[e];
    int p = atomicAdd(&cur[s], 1);
    eid[off[s] + p] = e;
}

// ---------------- fused B-compute + message scatter ----------------
// grid = NSLICE * NBLK blocks; block (sl, blk) handles o-slice sl and node
// groups blk, blk+NBLK, ... Each (edge, o) is produced exactly once.
__global__ __launch_bounds__(MSG_THREADS, 1)
void k_msg(const float* __restrict__ h, const float* __restrict__ g,
           const float* __restrict__ w2, const float* __restrict__ Cbuf,
           const int* __restrict__ ei, const int* __restrict__ csr_off,
           const int* __restrict__ csr_eid, float* __restrict__ agg) {
    extern __shared__ float lds[];
    float* W2s = lds;                        // [64][512]
    float* Bn  = lds + 64 * WCOLS;           // [8][520]
    float* hT  = Bn + GNODES * BSTRIDE;      // [64][8]
    __shared__ int offs[GNODES + 1];

    const int tid = threadIdx.x;
    const int sl  = blockIdx.x & (NSLICE - 1);
    const int blk = blockIdx.x >> 3;
    const int o0  = sl * OSUB;

    // stage W2 o-slice: W2s[i][k*8+ol] = w2[k*4096 + i*64 + o0+ol]
    for (int idx = tid; idx < 64 * WCOLS; idx += MSG_THREADS) {
        int i = idx >> 9;
        int c = idx & 511;
        int k = c >> 3, ol = c & 7;
        W2s[idx] = w2[(size_t)k * 4096 + i * 64 + o0 + ol];
    }
    __syncthreads();

    for (int grp = blk; grp < NGROUPS; grp += NBLK) {
        const int n0 = grp * GNODES;
        {   // hT[i][j] = h[n0+j][i]
            int j = tid & 7;
            int i = tid >> 3;
            hT[tid] = h[(size_t)(n0 + j) * 64 + i];
        }
        if (tid <= GNODES) offs[tid] = csr_off[n0 + tid];
        __syncthreads();

        // Bn[j][c] = sum_i hT[i][j] * W2s[i][c]   (c = thread's column)
        float acc[GNODES];
#pragma unroll
        for (int j = 0; j < GNODES; j++) acc[j] = 0.f;
#pragma unroll 4
        for (int i = 0; i < 64; i++) {
            const float w = W2s[i * WCOLS + tid];
            const float4 ha = *(const float4*)(hT + i * GNODES);
            const float4 hb = *(const float4*)(hT + i * GNODES + 4);
            acc[0] += w * ha.x; acc[1] += w * ha.y;
            acc[2] += w * ha.z; acc[3] += w * ha.w;
            acc[4] += w * hb.x; acc[5] += w * hb.y;
            acc[6] += w * hb.z; acc[7] += w * hb.w;
        }
#pragma unroll
        for (int j = 0; j < GNODES; j++) Bn[j * BSTRIDE + tid] = acc[j];
        __syncthreads();

        // edge phase: 64 subgroups of 8 threads; subgroup per edge slot
        const int P0 = offs[0];
        const int Etot = offs[GNODES] - P0;
        const int es = tid >> 3, ol = tid & 7;
        for (int slot = es; slot < Etot; slot += MSG_THREADS / OSUB) {
            const int gpos = P0 + slot;
            int j = 0;
#pragma unroll
            for (int q = 1; q < GNODES; q++) j += (gpos >= offs[q]) ? 1 : 0;
            const int e = csr_eid[gpos];
            const int dst = ei[NE + e];
            const float4* g4 = (const float4*)(g + (size_t)e * HID);
            const float* bj = Bn + j * BSTRIDE;
            float m = Cbuf[(size_t)(n0 + j) * 64 + o0 + ol];
#pragma unroll
            for (int k4 = 0; k4 < 16; k4++) {
                const float4 gv = g4[k4];
                m += gv.x * bj[(k4 * 4 + 0) * 8 + ol];
                m += gv.y * bj[(k4 * 4 + 1) * 8 + ol];
                m += gv.z * bj[(k4 * 4 + 2) * 8 + ol];
                m += gv.w * bj[(k4 * 4 + 3) * 8 + ol];
            }
            atomicAdd(&agg[(size_t)dst * 64 + o0 + ol], m);
        }
        __syncthreads();
    }
}

// ---------------- h_new = silu(agg*invdeg + h @ root_w + conv_b) ----------------
__global__ __launch_bounds__(256)
void k_final(const float* __restrict__ h, const float* __restrict__ agg,
             const float* __restrict__ invd, const float* __restrict__ rw,
             const float* __restrict__ cb, float* __restrict__ hout) {
    __shared__ float Ws[64 * 64];
    __shared__ float As[4 * 64];
    const int tid = threadIdx.x;
    for (int idx = tid; idx < 64 * 64; idx += 256) Ws[idx] = rw[idx];
    const int r0 = blockIdx.x * 4;
    As[tid] = h[(size_t)r0 * 64 + tid];
    __syncthreads();
    const int rr = tid >> 6, c = tid & 63;
    const int r = r0 + rr;
    float s = cb[c] + agg[(size_t)r * 64 + c] * invd[r];
#pragma unroll
    for (int k = 0; k < 64; k++) s += As[rr * 64 + k] * Ws[k * 64 + c];
    hout[(size_t)r * 64 + c] = silu_f(s);
}

// ---------------- global mean pool (accumulate) ----------------
__global__ void k_pool(const float* __restrict__ h, const int* __restrict__ batch,
                       float* __restrict__ hg, float* __restrict__ gcnt) {
    int idx = blockIdx.x * 256 + threadIdx.x;
    if (idx >= NN * 64) return;
    int n = idx >> 6, o = idx & 63;
    int b = batch[n];
    atomicAdd(&hg[b * 64 + o], h[idx]);
    if (o == 0) atomicAdd(&gcnt[b], 1.f);
}

// ---------------- head MLP: out[g] = silu(hg_mean @ w1 + b1) @ w2 + b2 ------------
__global__ __launch_bounds__(64)
void k_head(const float* __restrict__ hg, const float* __restrict__ gcnt,
            const float* __restrict__ w1, const float* __restrict__ b1,
            const float* __restrict__ w2, const float* __restrict__ b2,
            float* __restrict__ out) {
    __shared__ float hrow[64];
    const int gidx = blockIdx.x, t = threadIdx.x;
    const float inv = 1.f / fmaxf(gcnt[gidx], 1.f);
    hrow[t] = hg[gidx * 64 + t] * inv;
    __syncthreads();
    float s = b1[t];
#pragma unroll
    for (int k = 0; k < 64; k++) s += hrow[k] * w1[k * 64 + t];
    s = silu_f(s);
    float v = s * w2[t];
#pragma unroll
    for (int d = 32; d > 0; d >>= 1) v += __shfl_down(v, d);
    if (t == 0) out[gidx] = v + b2[0];
}

extern "C" void kernel_launch(void* const* d_in, const int* in_sizes, int n_in,
                              void* d_out, int out_size, void* d_ws, size_t ws_size,
                              hipStream_t stream) {
    const float* x     = (const float*)d_in[0];
    const float* ea    = (const float*)d_in[1];
    const int*   ei    = (const int*)  d_in[2];
    const int*   batch = (const int*)  d_in[3];
    const float* pw    = (const float*)d_in[4];
    const float* pb    = (const float*)d_in[5];
    const float* ew1   = (const float*)d_in[6];
    const float* eb1   = (const float*)d_in[7];
    const float* ew2   = (const float*)d_in[8];
    const float* eb2   = (const float*)d_in[9];
    const float* rw    = (const float*)d_in[10];
    const float* cb    = (const float*)d_in[11];
    const float* hw1   = (const float*)d_in[12];
    const float* hb1   = (const float*)d_in[13];
    const float* hw2   = (const float*)d_in[14];
    const float* hb2   = (const float*)d_in[15];
    float* out = (float*)d_out;

    float* ws = (float*)d_ws;
    size_t off = 0;
    auto alloc = [&](size_t n) {
        float* p = ws + off;
        off += (n + 63) & ~(size_t)63;
        return p;
    };
    float* hA   = alloc((size_t)NN * 64);
    float* hBuf = alloc((size_t)NN * 64);
    float* gbuf = alloc((size_t)NE * 64);
    float* Cbuf = alloc((size_t)NN * 64);
    float* agg  = alloc((size_t)NN * 64);
    float* degf = alloc(NN);
    float* invd = alloc(NN);
    float* hg   = alloc(64 * 64);
    float* gcnt = alloc(64);
    int* csr_off_ = (int*)alloc(NN + 1);
    int* csr_cnt  = (int*)alloc(NN);
    int* csr_cur  = (int*)alloc(NN);
    int* csr_eid  = (int*)alloc(NE);

    hipMemsetAsync(degf, 0, NN * sizeof(float), stream);
    hipMemsetAsync(csr_cnt, 0, NN * sizeof(int), stream);
    hipMemsetAsync(hg, 0, 64 * 64 * sizeof(float), stream);
    hipMemsetAsync(gcnt, 0, 64 * sizeof(float), stream);

    k_hist<<<dim3((NE + 255) / 256), dim3(256), 0, stream>>>(ei, degf, csr_cnt);
    k_invdeg<<<dim3((NN + 255) / 256), dim3(256), 0, stream>>>(degf, invd);
    k_scan<<<dim3(1), dim3(1024), 0, stream>>>(csr_cnt, csr_off_, csr_cur);
    k_fill<<<dim3((NE + 255) / 256), dim3(256), 0, stream>>>(ei, csr_off_, csr_cur, csr_eid);

    // h = x @ proj_w + proj_b
    k_rowmm<64, false, true><<<dim3(NN / 4), dim3(256), 0, stream>>>(x, pw, pb, hA, NN);

    const size_t MSG_LDS_BYTES = (size_t)MSG_LDS_FLOATS * sizeof(float);
    hipFuncSetAttribute(reinterpret_cast<const void*>(k_msg),
                        hipFuncAttributeMaxDynamicSharedMemorySize, (int)MSG_LDS_BYTES);

    float* hcur = hA;
    float* hnxt = hBuf;
    for (int l = 0; l < NLAYERS; l++) {
        // g = silu(edge_attr @ w1 + b1)
        k_rowmm<16, true, true><<<dim3(NE / 4), dim3(256), 0, stream>>>(
            ea, ew1 + (size_t)l * EDIM * 64, eb1 + (size_t)l * 64, gbuf, NE);
        // C = h @ b2(reshaped 64x64)
        k_rowmm<64, false, false><<<dim3(NN / 4), dim3(256), 0, stream>>>(
            hcur, eb2 + (size_t)l * 4096, nullptr, Cbuf, NN);
        hipMemsetAsync(agg, 0, (size_t)NN * 64 * sizeof(float), stream);
        k_msg<<<dim3(NSLICE * NBLK), dim3(MSG_THREADS), MSG_LDS_BYTES, stream>>>(
            hcur, gbuf, ew2 + (size_t)l * 64 * 4096, Cbuf, ei, csr_off_, csr_eid, agg);
        k_final<<<dim3(NN / 4), dim3(256), 0, stream>>>(
            hcur, agg, invd, rw + (size_t)l * 64 * 64, cb + (size_t)l * 64, hnxt);
        float* t = hcur; hcur = hnxt; hnxt = t;
    }

    k_pool<<<dim3((NN * 64) / 256), dim3(256), 0, stream>>>(hcur, batch, hg, gcnt);
    k_head<<<dim3(NGRAPH), dim3(64), 0, stream>>>(hg, gcnt, hw1, hb1, hw2, hb2, out);
}

// Round 2
// 1424.928 us; speedup vs baseline: 2.7203x; 2.7203x over previous
//
#include <hip/hip_runtime.h>
#include <math.h>

#define NN 10000
#define NE 40000
#define NGRAPH 64
#define HID 64
#define EDIM 16
#define NLAYERS 3

// ---- fused message kernel geometry ----
#define GNODES 8
#define NGROUPS (NN / GNODES)     // 1250
#define MSG_BLOCKS 250            // 5 groups per block exactly
#define MSG_THREADS 1024          // 16 waves, 1 block/CU (128KB LDS)
#define B_FLOATS (GNODES * 4096)  // 32768 floats = 128 KB
#define HS_FLOATS (64 * GNODES)   // h staging [i][j]
#define MSG_LDS_FLOATS (B_FLOATS + HS_FLOATS)

__device__ __forceinline__ float silu_f(float x) { return x / (1.f + expf(-x)); }

// ---------------- small row GEMM: out[M][64] = act(A[M][K] @ W[K][64] + bias) ----
template<int K, bool DO_SILU, bool HAS_BIAS>
__global__ __launch_bounds__(256)
void k_rowmm(const float* __restrict__ A, const float* __restrict__ W,
             const float* __restrict__ bias, float* __restrict__ out, int M) {
    __shared__ float Ws[K * 64];
    __shared__ float As[4 * K];
    const int tid = threadIdx.x;
    for (int idx = tid; idx < K * 64; idx += 256) Ws[idx] = W[idx];
    const int r0 = blockIdx.x * 4;
    for (int idx = tid; idx < 4 * K; idx += 256) {
        int r = r0 + idx / K;
        As[idx] = (r < M) ? A[(size_t)r * K + (idx % K)] : 0.f;
    }
    __syncthreads();
    const int rr = tid >> 6, c = tid & 63;
    const int r = r0 + rr;
    if (r >= M) return;
    float s = HAS_BIAS ? bias[c] : 0.f;
#pragma unroll
    for (int k = 0; k < K; k++) s += As[rr * K + k] * Ws[k * 64 + c];
    if (DO_SILU) s = silu_f(s);
    out[(size_t)r * 64 + c] = s;
}

// ---------------- degree histogram + src counts ----------------
__global__ void k_hist(const int* __restrict__ ei, float* __restrict__ degf,
                       int* __restrict__ cnt) {
    int e = blockIdx.x * 256 + threadIdx.x;
    if (e >= NE) return;
    int s = ei[e], d = ei[NE + e];
    atomicAdd(&cnt[s], 1);
    atomicAdd(&degf[d], 1.f);
}

__global__ void k_invdeg(const float* __restrict__ degf, float* __restrict__ invd) {
    int n = blockIdx.x * 256 + threadIdx.x;
    if (n < NN) {
        float d = degf[n];
        invd[n] = (d > 0.f) ? 1.f / d : 0.f;
    }
}

// ---------------- single-block exclusive scan over NN counts ----------------
__global__ __launch_bounds__(1024)
void k_scan(const int* __restrict__ cnt, int* __restrict__ off, int* __restrict__ cur) {
    __shared__ int part[1024];
    const int t = threadIdx.x;
    const int CH = (NN + 1023) / 1024;  // 10
    const int base0 = t * CH;
    int s = 0;
    for (int i = 0; i < CH; i++) {
        int idx = base0 + i;
        if (idx < NN) s += cnt[idx];
    }
    part[t] = s;
    __syncthreads();
    for (int d = 1; d < 1024; d <<= 1) {
        int v = (t >= d) ? part[t - d] : 0;
        __syncthreads();
        part[t] += v;
        __syncthreads();
    }
    int run = (t == 0) ? 0 : part[t - 1];
    for (int i = 0; i < CH; i++) {
        int idx = base0 + i;
        if (idx < NN) {
            off[idx] = run;
            run += cnt[idx];
            cur[idx] = 0;
        }
    }
    if (t == 1023) off[NN] = run;
}

__global__ void k_fill(const int* __restrict__ ei, const int* __restrict__ off,
                       int* __restrict__ cur, int* __restrict__ eid) {
    int e = blockIdx.x * 256 + threadIdx.x;
    if (e >= NE) return;
    int s = ei[e];
    int p = atomicAdd(&cur[s], 1);
    eid[off[s] + p] = e;
}

// ---------------- fused B-compute + message scatter (v2) ----------------
// B[n,k,o] = sum_i h[n,i]*w2[k, i*64+o] held in LDS for 8 nodes at a time,
// XOR-swizzled so the edge-phase ds_read_b128 gather is bank-spread.
// msg[e,o] = sum_k g[e,k]*B[src,k,o] + C[src,o], atomically scattered to agg[dst].
__global__ __launch_bounds__(MSG_THREADS, 4)
void k_msg(const float* __restrict__ h, const float* __restrict__ g,
           const float* __restrict__ w2, const float* __restrict__ Cbuf,
           const int* __restrict__ ei, const int* __restrict__ csr_off,
           const int* __restrict__ csr_eid, float* __restrict__ agg) {
    extern __shared__ float lds[];
    float* Bl  = lds;               // [8][4096] swizzled: (j,k,o) at j*4096+k*64+(o^(swz<<2))
    float* h_s = lds + B_FLOATS;    // [64][8]: h_s[i*8+j] = h[n0+j][i]
    __shared__ int offs[GNODES + 1];

    const int tid = threadIdx.x;
    const int o   = tid & 63;
    const int k00 = tid >> 6;       // 0..15; thread's k set = {k00, k00+16, k00+32, k00+48}

    const float* w2c0 = w2 + (size_t)(k00 +  0) * 4096 + o;
    const float* w2c1 = w2 + (size_t)(k00 + 16) * 4096 + o;
    const float* w2c2 = w2 + (size_t)(k00 + 32) * 4096 + o;
    const float* w2c3 = w2 + (size_t)(k00 + 48) * 4096 + o;

    const int q = tid & 3;                                     // edge-phase lane-in-quad
    const int obase_q = ((q & 1) << 4) | (((q >> 1) & 1) << 3); // reduce output o-base

    for (int grp = blockIdx.x; grp < NGROUPS; grp += MSG_BLOCKS) {
        const int n0 = grp * GNODES;
        __syncthreads();   // previous group fully consumed
        if (tid < 512) {
            int i = tid >> 3, j = tid & 7;
            h_s[i * 8 + j] = h[(size_t)(n0 + j) * 64 + i];
        }
        if (tid <= GNODES) offs[tid] = csr_off[n0 + tid];
        __syncthreads();

        // ---- B compute: acc[p][j] = B[n0+j][k_p][o] ----
        float acc[4][8];
#pragma unroll
        for (int p = 0; p < 4; ++p)
#pragma unroll
            for (int j = 0; j < 8; ++j) acc[p][j] = 0.f;

#pragma unroll 4
        for (int i = 0; i < 64; ++i) {
            const float4 ha = *(const float4*)(h_s + i * 8);
            const float4 hb = *(const float4*)(h_s + i * 8 + 4);
            const float w0 = w2c0[i * 64];
            const float w1 = w2c1[i * 64];
            const float w2v = w2c2[i * 64];
            const float w3 = w2c3[i * 64];
#define ACC8(P, WV) \
            acc[P][0] += (WV) * ha.x; acc[P][1] += (WV) * ha.y; \
            acc[P][2] += (WV) * ha.z; acc[P][3] += (WV) * ha.w; \
            acc[P][4] += (WV) * hb.x; acc[P][5] += (WV) * hb.y; \
            acc[P][6] += (WV) * hb.z; acc[P][7] += (WV) * hb.w;
            ACC8(0, w0) ACC8(1, w1) ACC8(2, w2v) ACC8(3, w3)
#undef ACC8
        }
        // write B (swizzled); per (p,j) lanes write a permutation of 64 consecutive
#pragma unroll
        for (int p = 0; p < 4; ++p) {
            const int k = k00 + p * 16;
            const int kh = k >> 3;
#pragma unroll
            for (int j = 0; j < 8; ++j) {
                const int swz = (kh ^ j) & 7;
                Bl[j * 4096 + k * 64 + (o ^ (swz << 2))] = acc[p][j];
            }
        }
        __syncthreads();

        // ---- edge phase: quad (4 lanes) per edge, k split 16/lane ----
        const int P0 = offs[0];
        const int Etot = offs[GNODES] - P0;
        for (int slot = (tid >> 2); slot < Etot; slot += MSG_THREADS / 4) {
            const int gpos = P0 + slot;
            int j = 0;
#pragma unroll
            for (int t = 1; t < GNODES; ++t) j += (gpos >= offs[t]) ? 1 : 0;
            const int e = csr_eid[gpos];
            const int dst = ei[NE + e];
            const float* gp = g + (size_t)e * 64 + q * 16;
            const float4 ga = *(const float4*)(gp);
            const float4 gb = *(const float4*)(gp + 4);
            const float4 gc = *(const float4*)(gp + 8);
            const float4 gd = *(const float4*)(gp + 12);
            const float garr[16] = {ga.x, ga.y, ga.z, ga.w, gb.x, gb.y, gb.z, gb.w,
                                    gc.x, gc.y, gc.z, gc.w, gd.x, gd.y, gd.z, gd.w};
            const float* Bj = Bl + j * 4096;

#pragma unroll
            for (int hh = 0; hh < 2; ++hh) {   // o in [hh*32, hh*32+32)
                float part[32];
#pragma unroll
                for (int t = 0; t < 32; ++t) part[t] = 0.f;
#pragma unroll
                for (int kk = 0; kk < 16; ++kk) {
                    const int k = q * 16 + kk;
                    const int sw = ((q * 2 + (kk >> 3)) ^ j) & 7;
                    const float4* row = (const float4*)(Bj + (k << 6));
                    const float gk = garr[kk];
#pragma unroll
                    for (int c = 0; c < 8; ++c) {
                        const int c4 = hh * 8 + c;
                        const float4 v = row[c4 ^ sw];
                        part[c * 4 + 0] += gk * v.x;
                        part[c * 4 + 1] += gk * v.y;
                        part[c * 4 + 2] += gk * v.z;
                        part[c * 4 + 3] += gk * v.w;
                    }
                }
                // halving reduce over the quad: mask 1 then mask 2
                float keep[16];
#pragma unroll
                for (int t = 0; t < 16; ++t) {
                    float lo = part[t]      + __shfl_xor(part[t], 1, 64);
                    float hi = part[16 + t] + __shfl_xor(part[16 + t], 1, 64);
                    keep[t] = (q & 1) ? hi : lo;
                }
                float r[8];
#pragma unroll
                for (int t = 0; t < 8; ++t) {
                    float a = keep[t]     + __shfl_xor(keep[t], 2, 64);
                    float b = keep[8 + t] + __shfl_xor(keep[8 + t], 2, 64);
                    r[t] = (q & 2) ? b : a;
                }
                const int ob = hh * 32 + obase_q;
                const float* Crow = Cbuf + (size_t)(n0 + j) * 64 + ob;
                const float4 c0 = *(const float4*)(Crow);
                const float4 c1 = *(const float4*)(Crow + 4);
                float* arow = agg + (size_t)dst * 64 + ob;
                atomicAdd(arow + 0, r[0] + c0.x);
                atomicAdd(arow + 1, r[1] + c0.y);
                atomicAdd(arow + 2, r[2] + c0.z);
                atomicAdd(arow + 3, r[3] + c0.w);
                atomicAdd(arow + 4, r[4] + c1.x);
                atomicAdd(arow + 5, r[5] + c1.y);
                atomicAdd(arow + 6, r[6] + c1.z);
                atomicAdd(arow + 7, r[7] + c1.w);
            }
        }
    }
}

// ---------------- h_new = silu(agg*invdeg + h @ root_w + conv_b) ----------------
__global__ __launch_bounds__(256)
void k_final(const float* __restrict__ h, const float* __restrict__ agg,
             const float* __restrict__ invd, const float* __restrict__ rw,
             const float* __restrict__ cb, float* __restrict__ hout) {
    __shared__ float Ws[64 * 64];
    __shared__ float As[4 * 64];
    const int tid = threadIdx.x;
    for (int idx = tid; idx < 64 * 64; idx += 256) Ws[idx] = rw[idx];
    const int r0 = blockIdx.x * 4;
    As[tid] = h[(size_t)r0 * 64 + tid];
    __syncthreads();
    const int rr = tid >> 6, c = tid & 63;
    const int r = r0 + rr;
    float s = cb[c] + agg[(size_t)r * 64 + c] * invd[r];
#pragma unroll
    for (int k = 0; k < 64; k++) s += As[rr * 64 + k] * Ws[k * 64 + c];
    hout[(size_t)r * 64 + c] = silu_f(s);
}

// ---------------- global mean pool (accumulate) ----------------
__global__ void k_pool(const float* __restrict__ h, const int* __restrict__ batch,
                       float* __restrict__ hg, float* __restrict__ gcnt) {
    int idx = blockIdx.x * 256 + threadIdx.x;
    if (idx >= NN * 64) return;
    int n = idx >> 6, o = idx & 63;
    int b = batch[n];
    atomicAdd(&hg[b * 64 + o], h[idx]);
    if (o == 0) atomicAdd(&gcnt[b], 1.f);
}

// ---------------- head MLP ----------------
__global__ __launch_bounds__(64)
void k_head(const float* __restrict__ hg, const float* __restrict__ gcnt,
            const float* __restrict__ w1, const float* __restrict__ b1,
            const float* __restrict__ w2, const float* __restrict__ b2,
            float* __restrict__ out) {
    __shared__ float hrow[64];
    const int gidx = blockIdx.x, t = threadIdx.x;
    const float inv = 1.f / fmaxf(gcnt[gidx], 1.f);
    hrow[t] = hg[gidx * 64 + t] * inv;
    __syncthreads();
    float s = b1[t];
#pragma unroll
    for (int k = 0; k < 64; k++) s += hrow[k] * w1[k * 64 + t];
    s = silu_f(s);
    float v = s * w2[t];
#pragma unroll
    for (int d = 32; d > 0; d >>= 1) v += __shfl_down(v, d);
    if (t == 0) out[gidx] = v + b2[0];
}

extern "C" void kernel_launch(void* const* d_in, const int* in_sizes, int n_in,
                              void* d_out, int out_size, void* d_ws, size_t ws_size,
                              hipStream_t stream) {
    const float* x     = (const float*)d_in[0];
    const float* ea    = (const float*)d_in[1];
    const int*   ei    = (const int*)  d_in[2];
    const int*   batch = (const int*)  d_in[3];
    const float* pw    = (const float*)d_in[4];
    const float* pb    = (const float*)d_in[5];
    const float* ew1   = (const float*)d_in[6];
    const float* eb1   = (const float*)d_in[7];
    const float* ew2   = (const float*)d_in[8];
    const float* eb2   = (const float*)d_in[9];
    const float* rw    = (const float*)d_in[10];
    const float* cb    = (const float*)d_in[11];
    const float* hw1   = (const float*)d_in[12];
    const float* hb1   = (const float*)d_in[13];
    const float* hw2   = (const float*)d_in[14];
    const float* hb2   = (const float*)d_in[15];
    float* out = (float*)d_out;

    float* ws = (float*)d_ws;
    size_t off = 0;
    auto alloc = [&](size_t n) {
        float* p = ws + off;
        off += (n + 63) & ~(size_t)63;
        return p;
    };
    float* hA   = alloc((size_t)NN * 64);
    float* hBuf = alloc((size_t)NN * 64);
    float* gbuf = alloc((size_t)NE * 64);
    float* Cbuf = alloc((size_t)NN * 64);
    float* agg  = alloc((size_t)NN * 64);
    float* degf = alloc(NN);
    float* invd = alloc(NN);
    float* hg   = alloc(64 * 64);
    float* gcnt = alloc(64);
    int* csr_off_ = (int*)alloc(NN + 1);
    int* csr_cnt  = (int*)alloc(NN);
    int* csr_cur  = (int*)alloc(NN);
    int* csr_eid  = (int*)alloc(NE);

    hipMemsetAsync(degf, 0, NN * sizeof(float), stream);
    hipMemsetAsync(csr_cnt, 0, NN * sizeof(int), stream);
    hipMemsetAsync(hg, 0, 64 * 64 * sizeof(float), stream);
    hipMemsetAsync(gcnt, 0, 64 * sizeof(float), stream);

    k_hist<<<dim3((NE + 255) / 256), dim3(256), 0, stream>>>(ei, degf, csr_cnt);
    k_invdeg<<<dim3((NN + 255) / 256), dim3(256), 0, stream>>>(degf, invd);
    k_scan<<<dim3(1), dim3(1024), 0, stream>>>(csr_cnt, csr_off_, csr_cur);
    k_fill<<<dim3((NE + 255) / 256), dim3(256), 0, stream>>>(ei, csr_off_, csr_cur, csr_eid);

    // h = x @ proj_w + proj_b
    k_rowmm<64, false, true><<<dim3(NN / 4), dim3(256), 0, stream>>>(x, pw, pb, hA, NN);

    const size_t MSG_LDS_BYTES = (size_t)MSG_LDS_FLOATS * sizeof(float);
    hipFuncSetAttribute(reinterpret_cast<const void*>(k_msg),
                        hipFuncAttributeMaxDynamicSharedMemorySize, (int)MSG_LDS_BYTES);

    float* hcur = hA;
    float* hnxt = hBuf;
    for (int l = 0; l < NLAYERS; l++) {
        // g = silu(edge_attr @ w1 + b1)
        k_rowmm<16, true, true><<<dim3(NE / 4), dim3(256), 0, stream>>>(
            ea, ew1 + (size_t)l * EDIM * 64, eb1 + (size_t)l * 64, gbuf, NE);
        // C = h @ b2(reshaped 64x64)
        k_rowmm<64, false, false><<<dim3(NN / 4), dim3(256), 0, stream>>>(
            hcur, eb2 + (size_t)l * 4096, nullptr, Cbuf, NN);
        hipMemsetAsync(agg, 0, (size_t)NN * 64 * sizeof(float), stream);
        k_msg<<<dim3(MSG_BLOCKS), dim3(MSG_THREADS), MSG_LDS_BYTES, stream>>>(
            hcur, gbuf, ew2 + (size_t)l * 64 * 4096, Cbuf, ei, csr_off_, csr_eid, agg);
        k_final<<<dim3(NN / 4), dim3(256), 0, stream>>>(
            hcur, agg, invd, rw + (size_t)l * 64 * 64, cb + (size_t)l * 64, hnxt);
        float* t = hcur; hcur = hnxt; hnxt = t;
    }

    k_pool<<<dim3((NN * 64) / 256), dim3(256), 0, stream>>>(hcur, batch, hg, gcnt);
    k_head<<<dim3(NGRAPH), dim3(64), 0, stream>>>(hg, gcnt, hw1, hb1, hw2, hb2, out);
}